// Round 4
// baseline (37.331 us; speedup 1.0000x reference)
//
#include <hip/hip_runtime.h>

#define NN 32
#define MAX_ITERS 10
#define RPT 2                   // rows per thread (register-pipelined)
#define TPB 256

// Projection math validated in R1/R2 (bit-exact algebraic form of reference):
//  forward = 31-step prefix-min; backward: q[u] = med3(p[u], max_child, q_fwd[u-1]).
__device__ __forceinline__ void project_row(const float4 a[8], float4 o[8]) {
    float p[NN], q[NN];
    #pragma unroll
    for (int k = 0; k < 8; ++k) {
        p[4*k+0] = a[k].x; p[4*k+1] = a[k].y;
        p[4*k+2] = a[k].z; p[4*k+3] = a[k].w;
    }
    // sigmoid via v_exp + v_rcp (1 ulp; error << threshold)
    #pragma unroll
    for (int i = 0; i < NN; ++i) {
        float e = __expf(-p[i]);
        p[i] = __builtin_amdgcn_rcpf(1.0f + e);
        q[i] = p[i];
    }
    for (int it = 0; it < MAX_ITERS; ++it) {
        #pragma unroll
        for (int u = 0; u < NN - 1; ++u)
            q[u + 1] = fminf(q[u + 1], q[u]);
        #pragma unroll
        for (int u = NN - 1; u >= 0; --u) {
            float maxc;
            if (u == NN - 1)      maxc = 0.0f;
            else if (u == NN - 2) maxc = q[NN - 1];
            else                  maxc = fmaxf(q[u + 1], q[u + 2]);
            float minp = (u == 0) ? 1.0f : q[u - 1];
            q[u] = __builtin_amdgcn_fmed3f(p[u], maxc, minp);
        }
    }
    #pragma unroll
    for (int k = 0; k < 8; ++k)
        o[k] = make_float4(q[4*k+0], q[4*k+1], q[4*k+2], q[4*k+3]);
}

// 2 rows/thread, register double-buffered: row k+1's global loads are issued
// BEFORE row k's compute, so the compiler waits only vmcnt(8) for row k and
// row k+1's reads stream in under row k's ~600-op compute chain. Row k's
// stores likewise drain under row k+1's compute. This breaks the phase-locked
// load->compute->store serialization of the single-generation grid.
__global__ __launch_bounds__(TPB) void dag_constraint_kernel(
    const float* __restrict__ x, float* __restrict__ out, int brows)
{
    const int tid = blockIdx.x * blockDim.x + threadIdx.x;
    const int nthreads = gridDim.x * blockDim.x;   // row stride between passes
    const float4* __restrict__ xg = reinterpret_cast<const float4*>(x);
    float4* __restrict__ og = reinterpret_cast<float4*>(out);

    // prologue: issue row 0's loads
    float4 a[8];
    long long r0 = tid;
    if (r0 < brows) {
        #pragma unroll
        for (int k = 0; k < 8; ++k) a[k] = xg[r0 * 8 + k];
    }

    #pragma unroll
    for (int rr = 0; rr < RPT; ++rr) {
        const long long r  = (long long)rr * nthreads + tid;
        const long long rn = r + nthreads;

        // issue next row's loads first (independent regs -> no wait)
        float4 b[8];
        if (rr + 1 < RPT && rn < brows) {
            #pragma unroll
            for (int k = 0; k < 8; ++k) b[k] = xg[rn * 8 + k];
        }

        if (r < brows) {
            float4 o[8];
            project_row(a, o);          // waits only on a's loads
            #pragma unroll
            for (int k = 0; k < 8; ++k) og[r * 8 + k] = o[k];  // fire-and-forget
        }

        #pragma unroll
        for (int k = 0; k < 8; ++k) a[k] = b[k];
    }
}

extern "C" void kernel_launch(void* const* d_in, const int* in_sizes, int n_in,
                              void* d_out, int out_size, void* d_ws, size_t ws_size,
                              hipStream_t stream)
{
    const float* x = (const float*)d_in[0];
    float* out = (float*)d_out;

    int total = in_sizes[0];      // B * N
    int brows = total / NN;       // B rows

    int threads_needed = (brows + RPT - 1) / RPT;
    int blocks = (threads_needed + TPB - 1) / TPB;

    dag_constraint_kernel<<<blocks, TPB, 0, stream>>>(x, out, brows);
}